// Round 6
// baseline (693.250 us; speedup 1.0000x reference)
//
#include <hip/hip_runtime.h>
#include <hip/hip_bf16.h>
#include <math.h>

// Problem constants: B,L,D_MODEL=(2,4096,1024), D_INNER=2048, D_CONV=4
#define B_SZ 2
#define L_SZ 4096
#define DM   1024
#define DI   2048
#define E_SZ 4096
#define DC   4

typedef unsigned short u16;
typedef __attribute__((ext_vector_type(8))) short short8;   // 8 bf16 = 4 VGPRs
typedef __attribute__((ext_vector_type(4))) float f32x4;

__device__ __forceinline__ float silu_f(float v) {
    return v / (1.0f + __expf(-v));
}

// split fp32 -> bf16 hi (truncate) + bf16 lo (truncate of exact residual)
__device__ __forceinline__ void split_bf16(float x, u16& h, u16& l) {
    unsigned u  = __float_as_uint(x);
    unsigned hb = u & 0xFFFF0000u;
    h = (u16)(hb >> 16);
    float lf = x - __uint_as_float(hb);
    l = (u16)(__float_as_uint(lf) >> 16);
}
__device__ __forceinline__ float bf2f(u16 h) {
    return __uint_as_float(((unsigned)h) << 16);
}

// async global->LDS 16B: HW dest = wave-uniform LDS base + lane*16
__device__ __forceinline__ void gld_lds16(const u16* g, u16* l) {
    __builtin_amdgcn_global_load_lds(
        (const __attribute__((address_space(1))) unsigned int*)g,
        (__attribute__((address_space(3))) unsigned int*)l, 16, 0, 0);
}

// ---------------------------------------------------------------------------
// ksplit: k_ssm (DI,L) fp32 -> kh/kl u16 planes (same layout).
// ---------------------------------------------------------------------------
__global__ __launch_bounds__(256) void ksplit(
    const float* __restrict__ k_ssm, u16* __restrict__ kh, u16* __restrict__ kl)
{
    const long i4 = ((long)blockIdx.x * 256 + threadIdx.x) * 4;
    float4 v = *(const float4*)&k_ssm[i4];
    float vv[4] = { v.x, v.y, v.z, v.w };
    unsigned long long hp = 0ull, lp = 0ull;
    #pragma unroll
    for (int r = 0; r < 4; ++r) {
        u16 h, l; split_bf16(vv[r], h, l);
        hp |= ((unsigned long long)h) << (16*r);
        lp |= ((unsigned long long)l) << (16*r);
    }
    *(unsigned long long*)&kh[i4] = hp;
    *(unsigned long long*)&kl[i4] = lp;
}

// ---------------------------------------------------------------------------
// pack_rm: fp32 row-major (R x K, k-contiguous, ldx) -> fragment-blocked split
// planes H/Lo laid out [K/32][R/16][512] (16x16x32 MFMA frag order).
// ---------------------------------------------------------------------------
__global__ __launch_bounds__(256) void pack_rm(
    const float* __restrict__ X, u16* __restrict__ H, u16* __restrict__ Lo,
    int ldx, int r16n, long sX, long sOut)
{
    const long cid = (long)blockIdx.x * 256 + threadIdx.x;
    const int  qc  = (int)(cid & 63);
    const long blk = cid >> 6;
    const int  r16 = (int)(blk % r16n);
    const int  k32 = (int)(blk / r16n);
    const int  q = qc >> 4, m = qc & 15;

    const float* src = X + blockIdx.y * sX + (long)(r16 * 16 + m) * ldx + k32 * 32 + q * 8;
    float4 v0 = *(const float4*)src;
    float4 v1 = *(const float4*)(src + 4);
    float v[8] = {v0.x,v0.y,v0.z,v0.w,v1.x,v1.y,v1.z,v1.w};

    u16 hs[8], ls[8];
    #pragma unroll
    for (int j = 0; j < 8; ++j) split_bf16(v[j], hs[j], ls[j]);

    const long o = blockIdx.y * sOut + cid * 8;
    *(uint4*)&H[o]  = *(const uint4*)hs;
    *(uint4*)&Lo[o] = *(const uint4*)ls;
}

// ---------------------------------------------------------------------------
// MFMA split-bf16 GEMM (unchanged from R3).
// ---------------------------------------------------------------------------
__global__ __launch_bounds__(256) void gemm_mfma(
    const u16* __restrict__ Ah, const u16* __restrict__ Al,
    const u16* __restrict__ Bh, const u16* __restrict__ Bl,
    float* __restrict__ C,
    int r16A, int r16B, long sA, long sB, long sC,
    int ldc, int nk32)
{
    __shared__ alignas(16) u16 sm[4][4096];

    const int tid  = threadIdx.x;
    const int wv   = tid >> 6, lane = tid & 63;
    const long zb  = blockIdx.z;

    const u16* srcs0 = Ah + zb * sA;
    const u16* srcs1 = Al + zb * sA;
    const u16* srcs2 = Bh + zb * sB;
    const u16* srcs3 = Bl + zb * sB;
    const u16* mysrc = (wv == 0) ? srcs0 : (wv == 1) ? srcs1 : (wv == 2) ? srcs2 : srcs3;
    const int  rblk  = (wv < 2) ? blockIdx.x * 8 : blockIdx.y * 8;
    const int  r16c  = (wv < 2) ? r16A : r16B;
    u16* myl = sm[wv];

    const int wr = wv >> 1, wc = wv & 1;

    f32x4 acc[4][4];
    #pragma unroll
    for (int i = 0; i < 4; ++i)
        #pragma unroll
        for (int j = 0; j < 4; ++j)
            #pragma unroll
            for (int r = 0; r < 4; ++r) acc[i][j][r] = 0.f;

    for (int s = 0; s < nk32; ++s) {
        if (s) __syncthreads();
        {
            const u16* g = mysrc + (((long)s * r16c + rblk) << 9) + lane * 8;
            #pragma unroll
            for (int i = 0; i < 8; ++i)
                gld_lds16(g + (i << 9), myl + (i << 9));
        }
        __syncthreads();

        short8 afh[4], afl[4], bfh[4], bfl[4];
        const int aoff = (wr * 4) * 512 + lane * 8;
        const int boff = (wc * 4) * 512 + lane * 8;
        #pragma unroll
        for (int t = 0; t < 4; ++t) {
            afh[t] = *(const short8*)&sm[0][aoff + t * 512];
            afl[t] = *(const short8*)&sm[1][aoff + t * 512];
            bfh[t] = *(const short8*)&sm[2][boff + t * 512];
            bfl[t] = *(const short8*)&sm[3][boff + t * 512];
        }
        #pragma unroll
        for (int i = 0; i < 4; ++i)
            #pragma unroll
            for (int j = 0; j < 4; ++j) {
                acc[i][j] = __builtin_amdgcn_mfma_f32_16x16x32_bf16(afh[i], bfh[j], acc[i][j], 0, 0, 0);
                acc[i][j] = __builtin_amdgcn_mfma_f32_16x16x32_bf16(afh[i], bfl[j], acc[i][j], 0, 0, 0);
                acc[i][j] = __builtin_amdgcn_mfma_f32_16x16x32_bf16(afl[i], bfh[j], acc[i][j], 0, 0, 0);
            }
    }

    const int m_ = lane & 15, q_ = lane >> 4;
    float* Cb = C + zb * sC;
    const int row00 = blockIdx.x * 128 + wr * 64 + q_ * 4;
    const int col0  = blockIdx.y * 128 + wc * 64 + m_;
    #pragma unroll
    for (int i = 0; i < 4; ++i)
        #pragma unroll
        for (int j = 0; j < 4; ++j) {
            const long base = (long)(row00 + i * 16) * ldc + col0 + j * 16;
            #pragma unroll
            for (int r = 0; r < 4; ++r)
                Cb[base + (long)r * ldc] = acc[i][j][r];
        }
}

// ---------------------------------------------------------------------------
// Depthwise causal conv4 + SiLU -> split bf16 planes (B,DI,L).
// ---------------------------------------------------------------------------
__global__ __launch_bounds__(256) void conv_silu_split(
    const float* __restrict__ xz, const float* __restrict__ conv_w,
    const float* __restrict__ conv_b,
    u16* __restrict__ xh_gl, u16* __restrict__ xl_gl)
{
    const long gid = (long)blockIdx.x * 256 + threadIdx.x;
    const int  q   = (int)(gid % (L_SZ / 4));
    const long bc  = gid / (L_SZ / 4);
    const int  ch  = (int)(bc % DI);
    const int  b   = (int)(bc / DI);

    const float* row = xz + ((long)b * E_SZ + ch) * L_SZ;
    const int l0 = q * 4;

    float4 cur  = *(const float4*)&row[l0];
    float4 prev = q ? *(const float4*)&row[l0 - 4] : make_float4(0.f, 0.f, 0.f, 0.f);

    const float w0 = conv_w[ch*DC+0], w1 = conv_w[ch*DC+1];
    const float w2 = conv_w[ch*DC+2], w3 = conv_w[ch*DC+3];
    const float bias = conv_b[ch];

    float o[4];
    o[0] = silu_f(bias + w0*prev.y + w1*prev.z + w2*prev.w + w3*cur.x);
    o[1] = silu_f(bias + w0*prev.z + w1*prev.w + w2*cur.x  + w3*cur.y);
    o[2] = silu_f(bias + w0*prev.w + w1*cur.x  + w2*cur.y  + w3*cur.z);
    o[3] = silu_f(bias + w0*cur.x  + w1*cur.y  + w2*cur.z  + w3*cur.w);

    unsigned long long hp = 0ull, lp = 0ull;
    #pragma unroll
    for (int r = 0; r < 4; ++r) {
        u16 h, l; split_bf16(o[r], h, l);
        hp |= ((unsigned long long)h) << (16*r);
        lp |= ((unsigned long long)l) << (16*r);
    }
    const long base = ((long)b * DI + ch) * L_SZ + l0;
    *(unsigned long long*)&xh_gl[base] = hp;
    *(unsigned long long*)&xl_gl[base] = lp;
}

// ---------------------------------------------------------------------------
// MFMA long causal conv v2: ONE wave per (b,ch).
//  - LDS 17.4 KB/block -> ~9 blocks/CU resident
//  - k gathered from pre-split kh/kl u16 planes (no split VALU in hot loop)
//  - chunk 0 guarded; chunks 1..127 guard-free (ki in [17,4095] provably)
//  - staging via global_load_lds 16B; explicit s_waitcnt(0) before use
//    (single-wave block: do not rely on __syncthreads to drain vmcnt)
// Epilogue writes split-bf16 y in place over consumed xh/xl rows.
// ---------------------------------------------------------------------------
__global__ __launch_bounds__(64) void longconv_mfma(
    u16* __restrict__ xh_gl, u16* __restrict__ xl_gl,
    const float* __restrict__ xz,
    const u16* __restrict__ kh_gl, const u16* __restrict__ kl_gl,
    const float* __restrict__ D_skip)
{
    __shared__ alignas(16) u16 XH[4352];   // 256 zero-pad + 4096
    __shared__ alignas(16) u16 XL[4352];

    const int lane = threadIdx.x;
    const int wc   = blockIdx.x;
    const int ch   = wc & (DI - 1);
    const int b    = wc >> 11;

    u16*       xhr = xh_gl + ((long)b * DI + ch) * L_SZ;
    u16*       xlr = xl_gl + ((long)b * DI + ch) * L_SZ;
    const u16* khr = kh_gl + (long)ch * L_SZ;
    const u16* klr = kl_gl + (long)ch * L_SZ;

    // zero pad + async staging
    if (lane < 32) {
        uint4 z = make_uint4(0u, 0u, 0u, 0u);
        *(uint4*)&XH[lane * 8] = z;
        *(uint4*)&XL[lane * 8] = z;
    }
    #pragma unroll
    for (int it = 0; it < 8; ++it) {
        gld_lds16(xhr + it * 512 + lane * 8, &XH[256 + it * 512]);
        gld_lds16(xlr + it * 512 + lane * 8, &XL[256 + it * 512]);
    }
    __builtin_amdgcn_s_waitcnt(0);   // drain vmcnt (global_load_lds) + lgkm
    __syncthreads();

    const int m_ = lane & 15;
    const int q_ = lane >> 4;
    const int dq = m_ - 8 * q_ + ((q_ >= 2) ? 32 : 0);          // [-8, 31]
    const int xoff_lane = 256 + 16 * m_ + 8 * q_ - ((q_ >= 2) ? 32 : 0);

    f32x4 acc[16];
    #pragma unroll
    for (int t = 0; t < 16; ++t)
        #pragma unroll
        for (int r = 0; r < 4; ++r) acc[t][r] = 0.f;

    // prefetch k fragment for c=0 (guarded: ki in [-15, 31])
    u16 knh[8], knl[8];
    #pragma unroll
    for (int e = 0; e < 8; ++e) {
        const int ki = dq - e;
        knh[e] = (ki >= 0) ? khr[ki] : (u16)0;
        knl[e] = (ki >= 0) ? klr[ki] : (u16)0;
    }

    for (int c = 0; c < 128; ++c) {
        short8 ah, al;
        #pragma unroll
        for (int e = 0; e < 8; ++e) { ah[e] = (short)knh[e]; al[e] = (short)knl[e]; }

        if (c < 127) {   // prefetch next (guard-free: ki in [17,4095])
            const int kb = 32 * (c + 1) + dq;
            #pragma unroll
            for (int e = 0; e < 8; ++e) {
                knh[e] = khr[kb - e];
                knl[e] = klr[kb - e];
            }
        }

        const int xbase = xoff_lane - 32 * c;
        #pragma unroll
        for (int t = 0; t < 16; ++t) {
            if (8 * t >= c - 7) {                       // causality (wave-uniform)
                short8 bh = *(const short8*)&XH[xbase + 256 * t];
                short8 bl = *(const short8*)&XL[xbase + 256 * t];
                acc[t] = __builtin_amdgcn_mfma_f32_16x16x32_bf16(ah, bh, acc[t], 0, 0, 0);
                acc[t] = __builtin_amdgcn_mfma_f32_16x16x32_bf16(ah, bl, acc[t], 0, 0, 0);
                acc[t] = __builtin_amdgcn_mfma_f32_16x16x32_bf16(al, bh, acc[t], 0, 0, 0);
            }
        }
    }

    // epilogue: y = (conv + D_skip*x) * silu(z) -> split bf16, in-place rows
    const float  Ds   = D_skip[ch];
    const float* zrow = xz + ((long)b * E_SZ + DI + ch) * L_SZ;

    #pragma unroll
    for (int t = 0; t < 16; ++t) {
        const int l0 = 256 * t + 16 * m_ + 4 * q_;
        float4 zv = *(const float4*)&zrow[l0];
        float zt[4] = { zv.x, zv.y, zv.z, zv.w };
        unsigned long long hp = 0ull, lp = 0ull;
        #pragma unroll
        for (int r = 0; r < 4; ++r) {
            const float xf = bf2f(XH[256 + l0 + r]) + bf2f(XL[256 + l0 + r]);
            const float o  = (acc[t][r] + Ds * xf) * silu_f(zt[r]);
            u16 h, l; split_bf16(o, h, l);
            hp |= ((unsigned long long)h) << (16*r);
            lp |= ((unsigned long long)l) << (16*r);
        }
        *(unsigned long long*)&xhr[l0] = hp;
        *(unsigned long long*)&xlr[l0] = lp;
    }
}

// ---------------------------------------------------------------------------
// pack_y: y split planes (B,DI,L) u16 -> GEMM2 A-operand fragment-blocked
// [K/32=64][L/16=256][512] per batch, via LDS transpose tile (32h x 128l).
// ---------------------------------------------------------------------------
__global__ __launch_bounds__(256) void pack_y(
    const u16* __restrict__ Yh, const u16* __restrict__ Yl,
    u16* __restrict__ OH, u16* __restrict__ OL, long sOut)
{
    __shared__ u16 T[2][32][136];
    const int t  = threadIdx.x;
    const int l0 = blockIdx.x * 128;
    const int h0 = blockIdx.y * 32;
    const int b  = blockIdx.z;

    const u16* yb_h = Yh + ((long)b * DI + h0) * L_SZ + l0;
    const u16* yb_l = Yl + ((long)b * DI + h0) * L_SZ + l0;

    #pragma unroll
    for (int i = 0; i < 2; ++i) {
        const int c = t + 256 * i;
        const int row = c >> 4, col = (c & 15) * 8;
        *(uint4*)&T[0][row][col] = *(const uint4*)&yb_h[(long)row * L_SZ + col];
        *(uint4*)&T[1][row][col] = *(const uint4*)&yb_l[(long)row * L_SZ + col];
    }
    __syncthreads();

    u16* outs[2] = { OH + b * sOut, OL + b * sOut };
    #pragma unroll
    for (int p = 0; p < 2; ++p) {
        #pragma unroll
        for (int i = 0; i < 2; ++i) {
            const int c = t + 256 * i;
            const int r16b = c >> 6, qc = c & 63;
            const int q = qc >> 4, m = qc & 15;
            const int l = r16b * 16 + m;
            u16 vals[8];
            #pragma unroll
            for (int j = 0; j < 8; ++j) vals[j] = T[p][q * 8 + j][l];
            const long o = ((long)(blockIdx.y * 256 + blockIdx.x * 8 + r16b) << 9) + qc * 8;
            *(uint4*)&outs[p][o] = *(const uint4*)vals;
        }
    }
}

// ---------------------------------------------------------------------------
extern "C" void kernel_launch(void* const* d_in, const int* in_sizes, int n_in,
                              void* d_out, int out_size, void* d_ws, size_t ws_size,
                              hipStream_t stream)
{
    const float* hidden = (const float*)d_in[0];  // (B, L, DM)
    const float* W_in   = (const float*)d_in[1];  // (E, DM)
    const float* conv_w = (const float*)d_in[2];  // (DI, 4)
    const float* conv_b = (const float*)d_in[3];  // (DI)
    const float* k_ssm  = (const float*)d_in[4];  // (DI, L)
    const float* D_skip = (const float*)d_in[5];  // (DI)
    const float* W_out  = (const float*)d_in[6];  // (DM, DI)
    float* out = (float*)d_out;                   // (B, L, DM)

    // ---- workspace layout (bytes), total 251,658,240 <= 256 MiB ----
    // xz fp32 (B,E,L)                 @ 0            134,217,728
    // xh u16  (B,DI,L)                @ 134,217,728   33,554,432  (becomes y-hi)
    // xl u16  (B,DI,L)                @ 167,772,160   33,554,432  (becomes y-lo)
    // slotA: Win packs -> Wout packs  @ 201,326,592   16,777,216
    // slotB: hidden packs -> kh/kl    @ 218,103,808   33,554,432
    //        (hidden packs dead after GEMM1; ksplit runs AFTER GEMM1)
    // yA packs alias xz x-halves (dead after longconv)
    char* ws = (char*)d_ws;
    float* xz  = (float*)ws;
    u16*   xh  = (u16*)(ws + 134217728);
    u16*   xl  = (u16*)(ws + 167772160);
    u16*   WinH  = (u16*)(ws + 201326592);
    u16*   WinL  = WinH + 4194304;            // 2 planes x 8,388,608 B
    u16*   WoutH = (u16*)(ws + 201326592);    // reused after GEMM1
    u16*   WoutL = WoutH + 2097152;           // 2 planes x 4,194,304 B
    u16*   hidH  = (u16*)(ws + 218103808);
    u16*   hidL  = hidH + 8388608;            // 2 planes x 16,777,216 B
    u16*   khp   = (u16*)(ws + 218103808);    // reuses hidden-pack slot
    u16*   klp   = khp + 8388608;             // 2 planes x 16,777,216 B
    u16*   yAh   = (u16*)ws;                  // aliases xz x-halves
    u16*   yAl   = yAh + 8388608;

    // 1) pack W_in and hidden
    pack_rm<<<dim3(2048, 1), 256, 0, stream>>>(W_in, WinH, WinL, DM, 256, 0L, 0L);
    pack_rm<<<dim3(2048, B_SZ), 256, 0, stream>>>(hidden, hidH, hidL, DM, 256,
        (long)L_SZ * DM, 4194304L);

    // 2) GEMM1: xz[b,e,l] = sum_d W_in[e,d]*hidden[b,l,d]
    gemm_mfma<<<dim3(32, 32, B_SZ), 256, 0, stream>>>(
        WinH, WinL, hidH, hidL, xz,
        256, 256, 0L, 4194304L, (long)E_SZ * L_SZ, L_SZ, 32);

    // 3) pre-split k into slotB (hidden packs now dead)
    ksplit<<<dim3((DI * L_SZ) / 1024), 256, 0, stream>>>(k_ssm, khp, klp);

    // 4) depthwise causal conv4 + SiLU -> split bf16 x
    conv_silu_split<<<dim3((unsigned)((long)B_SZ*DI*(L_SZ/4)/256)), 256, 0, stream>>>(
        xz, conv_w, conv_b, xh, xl);

    // 5) MFMA long causal conv + D_skip + silu(z) -> y split, in-place in xh/xl
    longconv_mfma<<<dim3(B_SZ * DI), 64, 0, stream>>>(
        xh, xl, xz, khp, klp, D_skip);

    // 6) pack W_out into slotA (Win packs now dead)
    pack_rm<<<dim3(1024, 1), 256, 0, stream>>>(W_out, WoutH, WoutL, DI, 64, 0L, 0L);

    // 7) pack y -> GEMM2 A-operand blocked (into dead xz x-half region)
    pack_y<<<dim3(32, 64, B_SZ), 256, 0, stream>>>(
        xh, xl, yAh, yAl, 33554432L);

    // 8) GEMM2: out[b,l,d] = sum_h y[b,h,l]*W_out[d,h]
    gemm_mfma<<<dim3(32, 8, B_SZ), 256, 0, stream>>>(
        yAh, yAl, WoutH, WoutL, out,
        256, 64, 33554432L, 0L, (long)L_SZ * DM, DM, 64);
}